// Round 6
// baseline (1596.353 us; speedup 1.0000x reference)
//
#include <hip/hip_runtime.h>

#define U_CNT 100000
#define I_CNT 50000
#define D_DIM 64
#define N_NODES 150000            // U + I
#define CHUNK 4096                // edges per block in passes A/B
#define NBKT 586                  // ceil(N_NODES/256) coarse buckets (256 nodes each)
#define CCAP 3584                 // LDS edge cache per bucket (max bucket ~3.4K)

// ---------- bf16 helpers ----------
__device__ __forceinline__ float blo(unsigned u) { return __uint_as_float(u << 16); }
__device__ __forceinline__ float bhi(unsigned u) { return __uint_as_float(u & 0xFFFF0000u); }
__device__ __forceinline__ unsigned f2b(float f) {  // fp32 -> bf16 bits, RNE
    unsigned b = __float_as_uint(f);
    return (b + 0x7FFFu + ((b >> 16) & 1u)) >> 16;
}
__device__ __forceinline__ unsigned pack2(float a, float b) {
    return f2b(a) | (f2b(b) << 16);
}

// ---------- Pass A: coarse LDS histogram -> global bucket counts (+ fused convert) ----------
__global__ void bucket_hist(const int* __restrict__ dst, int* __restrict__ bCnt,
                            int nE,
                            const float4* __restrict__ user4,
                            const float4* __restrict__ item4,
                            uint2* __restrict__ ego0, int n4u, int n4) {
    __shared__ int h[NBKT];
    for (int i = threadIdx.x; i < NBKT; i += blockDim.x) h[i] = 0;
    __syncthreads();
    int b = blockIdx.x;
    int beg = b * CHUNK, end = min(nE, beg + CHUNK);
    for (int e = beg + (int)threadIdx.x; e < end; e += blockDim.x)
        atomicAdd(&h[dst[e] >> 8], 1);
    __syncthreads();
    for (int i = threadIdx.x; i < NBKT; i += blockDim.x)
        if (h[i] > 0) atomicAdd(&bCnt[i], h[i]);
    // fused streaming fp32->bf16 convert (independent work; this kernel is light)
    int gsz = gridDim.x * blockDim.x;
    for (int i = blockIdx.x * blockDim.x + threadIdx.x; i < n4; i += gsz) {
        float4 f = (i < n4u) ? user4[i] : item4[i - n4u];
        ego0[i] = make_uint2(pack2(f.x, f.y), pack2(f.z, f.w));
    }
}

// ---------- exclusive scan of 586 bucket counts (single block) ----------
__global__ void scan586(const int* __restrict__ bCnt, int* __restrict__ bBase, int nE) {
    __shared__ int sm[1024];
    int t = threadIdx.x;
    int v = (t < NBKT) ? bCnt[t] : 0;
    sm[t] = v;
    __syncthreads();
    for (int off = 1; off < 1024; off <<= 1) {
        int x = (t >= off) ? sm[t - off] : 0;
        __syncthreads();
        sm[t] += x;
        __syncthreads();
    }
    if (t < NBKT) bBase[t] = sm[t] - v;  // exclusive
    if (t == 0) bBase[NBKT] = nE;
}

// ---------- Pass B: two-pass scatter with global range reservation ----------
// record: x = src (18b) | fine (8b) << 18 ; y = val bits
__global__ void bucket_scatter(const int* __restrict__ src, const int* __restrict__ dst,
                               const float* __restrict__ val,
                               const int* __restrict__ bBase, int* __restrict__ bCursor,
                               uint2* __restrict__ tmp, int nE) {
    __shared__ int cnt[NBKT];
    __shared__ int cur[NBKT];
    int b = blockIdx.x;
    for (int i = threadIdx.x; i < NBKT; i += blockDim.x) cnt[i] = 0;
    __syncthreads();
    int beg = b * CHUNK, end = min(nE, beg + CHUNK);
    for (int e = beg + (int)threadIdx.x; e < end; e += blockDim.x)
        atomicAdd(&cnt[dst[e] >> 8], 1);
    __syncthreads();
    for (int i = threadIdx.x; i < NBKT; i += blockDim.x) {
        int c = cnt[i];
        cur[i] = (c > 0) ? (bBase[i] + atomicAdd(&bCursor[i], c)) : 0;
    }
    __syncthreads();
    for (int e = beg + (int)threadIdx.x; e < end; e += blockDim.x) {
        int d = dst[e];
        int pos = atomicAdd(&cur[d >> 8], 1);
        tmp[pos] = make_uint2((unsigned)src[e] | ((unsigned)(d & 255) << 18),
                              __float_as_uint(val[e]));
    }
}

// ---------- Pass C: per-bucket sort by (half | src-class) ----------
// key = (fine>>7)<<7 | (src>>11).  src-class = 2048-node band (256 KB of ego).
// All SpMM blocks then sweep src-space coherently -> gather working set becomes
// a narrow band instead of the whole 19.2 MB table.
__global__ void bucket_sort(const int* __restrict__ bBase, const uint2* __restrict__ tmp,
                            uint2* __restrict__ csr, int* __restrict__ hSplit, int nE) {
    __shared__ int hist[256];
    __shared__ int scanb[256];
    __shared__ int cur[256];
    __shared__ uint2 cache[CCAP];
    int bkt  = blockIdx.x;
    int base = bBase[bkt];
    int endp = bBase[bkt + 1];
    int size = endp - base;
    int t = threadIdx.x;
    hist[t] = 0;
    __syncthreads();
    bool cached = (size <= CCAP);
    for (int k = t; k < size; k += blockDim.x) {
        uint2 r = tmp[base + k];
        if (cached) cache[k] = r;
        int key = (int)(((r.x >> 18) & 128u) | ((r.x & 0x3FFFFu) >> 11));
        atomicAdd(&hist[key], 1);
    }
    __syncthreads();
    int v = hist[t];
    scanb[t] = v;
    __syncthreads();
    for (int off = 1; off < 256; off <<= 1) {
        int x = (t >= off) ? scanb[t - off] : 0;
        __syncthreads();
        scanb[t] += x;
        __syncthreads();
    }
    cur[t] = scanb[t] - v;  // exclusive
    if (t == 255) hSplit[bkt] = base + scanb[127];  // edges with fine < 128
    __syncthreads();
    for (int k = t; k < size; k += blockDim.x) {
        uint2 r = cached ? cache[k] : tmp[base + k];
        int key = (int)(((r.x >> 18) & 128u) | ((r.x & 0x3FFFFu) >> 11));
        int p = atomicAdd(&cur[key], 1);
        csr[base + p] = r;
    }
}

// ---------- edge-parallel SpMM: 128-node tile in LDS fp32, class-swept gathers ----------
// Each block owns half a bucket (128 dst nodes, 32 KB acc -> 4 blocks/CU).
// 8 lanes/edge gather 16 B each; fp32 LDS atomicAdd with XOR-dim swizzle to
// randomize bank sets across the 8 concurrent edges of a wave.
template <int FINAL>
__global__ __launch_bounds__(256, 4)
void lgcn_spmm(const int* __restrict__ bBase, const int* __restrict__ hSplit,
               const uint2* __restrict__ csr,
               const uint4* __restrict__ ego_in, uint4* __restrict__ ego_out,
               const uint4* __restrict__ egoA, const uint4* __restrict__ egoB,
               float4* __restrict__ out) {
    __shared__ float acc[128 * 64];  // 32 KB
    int bid  = blockIdx.x;
    int bkt  = bid >> 1;
    int half = bid & 1;
    int b0 = bBase[bkt], b1 = bBase[bkt + 1], hs = hSplit[bkt];
    int beg = half ? hs : b0;
    int end = half ? b1 : hs;
    int t = threadIdx.x;
#pragma unroll
    for (int i = 0; i < 32; ++i) acc[t + 256 * i] = 0.0f;
    __syncthreads();

    int g = t >> 3;        // edge-group 0..31
    int l = t & 7;         // 8-dim chunk within row
    int d0 = l * 8;
    for (int k = beg + g; k < end; k += 128) {
#pragma unroll
        for (int u = 0; u < 4; ++u) {
            int kk = k + u * 32;
            int kks = (kk < end) ? kk : beg;       // loop entered => beg < end, safe
            uint2 r = csr[kks];
            float w = (kk < end) ? __uint_as_float(r.y) : 0.0f;
            int src = (int)(r.x & 0x3FFFFu);
            int fl  = (int)((r.x >> 18) & 127u);   // fine local to this half
            int f6  = fl & 63;
            uint4 gv = ego_in[(size_t)src * 8 + l];
            float* a = &acc[fl * 64];
            atomicAdd(&a[(d0 + 0) ^ f6], w * blo(gv.x));
            atomicAdd(&a[(d0 + 1) ^ f6], w * bhi(gv.x));
            atomicAdd(&a[(d0 + 2) ^ f6], w * blo(gv.y));
            atomicAdd(&a[(d0 + 3) ^ f6], w * bhi(gv.y));
            atomicAdd(&a[(d0 + 4) ^ f6], w * blo(gv.z));
            atomicAdd(&a[(d0 + 5) ^ f6], w * bhi(gv.z));
            atomicAdd(&a[(d0 + 6) ^ f6], w * blo(gv.w));
            atomicAdd(&a[(d0 + 7) ^ f6], w * bhi(gv.w));
        }
    }
    __syncthreads();

    int nodebase = bkt * 256 + half * 128;
    for (int n = g; n < 128; n += 32) {
        int node = nodebase + n;
        if (node >= N_NODES) break;
        const float* a = &acc[n * 64];
        int f6 = n & 63;
        float v0 = a[(d0 + 0) ^ f6], v1 = a[(d0 + 1) ^ f6];
        float v2 = a[(d0 + 2) ^ f6], v3 = a[(d0 + 3) ^ f6];
        float v4 = a[(d0 + 4) ^ f6], v5 = a[(d0 + 5) ^ f6];
        float v6 = a[(d0 + 6) ^ f6], v7 = a[(d0 + 7) ^ f6];
        if (!FINAL) {
            uint4 rr;
            rr.x = pack2(v0, v1); rr.y = pack2(v2, v3);
            rr.z = pack2(v4, v5); rr.w = pack2(v6, v7);
            ego_out[(size_t)node * 8 + l] = rr;
        } else {
            uint4 a2 = egoA[(size_t)node * 8 + l];
            uint4 b2 = egoB[(size_t)node * 8 + l];
            const float s = 1.0f / 3.0f;
            float4 o0, o1;
            o0.x = (blo(a2.x) + blo(b2.x) + v0) * s;
            o0.y = (bhi(a2.x) + bhi(b2.x) + v1) * s;
            o0.z = (blo(a2.y) + blo(b2.y) + v2) * s;
            o0.w = (bhi(a2.y) + bhi(b2.y) + v3) * s;
            o1.x = (blo(a2.z) + blo(b2.z) + v4) * s;
            o1.y = (bhi(a2.z) + bhi(b2.z) + v5) * s;
            o1.z = (blo(a2.w) + blo(b2.w) + v6) * s;
            o1.w = (bhi(a2.w) + bhi(b2.w) + v7) * s;
            size_t ob = (size_t)node * 16 + 2 * l;
            out[ob]     = o0;
            out[ob + 1] = o1;
        }
    }
}

static inline size_t align_up(size_t x, size_t a) { return (x + a - 1) & ~(a - 1); }

extern "C" void kernel_launch(void* const* d_in, const int* in_sizes, int n_in,
                              void* d_out, int out_size, void* d_ws, size_t ws_size,
                              hipStream_t stream) {
    const float* user_emb  = (const float*)d_in[0];
    const float* item_emb  = (const float*)d_in[1];
    const int*   edge_src  = (const int*)d_in[2];
    const int*   edge_dst  = (const int*)d_in[3];
    const float* edge_vals = (const float*)d_in[4];
    const int    nE        = in_sizes[2];  // 2E = 1.2M

    float* out = (float*)d_out;
    const size_t nd = (size_t)N_NODES * D_DIM;

    const int NB_B = (nE + CHUNK - 1) / CHUNK;  // 293

    // ---- ws layout ----
    size_t off = 0;
    char* base = (char*)d_ws;
    uint2* csr     = (uint2*)(base + off); off = align_up(off + (size_t)nE * sizeof(uint2), 256);
    uint2* tmp     = (uint2*)(base + off); off = align_up(off + (size_t)nE * sizeof(uint2), 256);
    int*   bCnt    = (int*)(base + off);   off = align_up(off + (size_t)NBKT * 4, 256);
    int*   bCursor = (int*)(base + off);   off = align_up(off + (size_t)NBKT * 4, 256);
    int*   bBase   = (int*)(base + off);   off = align_up(off + (size_t)(NBKT + 1) * 4, 256);
    int*   hSplit  = (int*)(base + off);   off = align_up(off + (size_t)NBKT * 4, 256);
    uint4* ego0    = (uint4*)(base + off); off = align_up(off + (size_t)N_NODES * 128, 256);
    uint4* ego_a   = (uint4*)(base + off); off = align_up(off + (size_t)N_NODES * 128, 256);
    uint4* ego_b   = (uint4*)(base + off); off = align_up(off + (size_t)N_NODES * 128, 256);

    const int block = 256;
    const int n4  = (int)(nd / 4);
    const int n4u = U_CNT * D_DIM / 4;

    // ---- CSR build: hist -> scan -> reserve+scatter -> class sort ----
    hipMemsetAsync(bCnt, 0, 2 * align_up((size_t)NBKT * 4, 256), stream);  // bCnt + bCursor
    bucket_hist<<<NB_B, block, 0, stream>>>(edge_dst, bCnt, nE,
        (const float4*)user_emb, (const float4*)item_emb, (uint2*)ego0, n4u, n4);
    scan586<<<1, 1024, 0, stream>>>(bCnt, bBase, nE);
    bucket_scatter<<<NB_B, block, 0, stream>>>(edge_src, edge_dst, edge_vals,
                                               bBase, bCursor, tmp, nE);
    bucket_sort<<<NBKT, block, 0, stream>>>(bBase, tmp, csr, hSplit, nE);

    // ---- 3 SpMM layers (edge-parallel, LDS fp32 accum, class-coherent gathers) ----
    const int spmm_grid = NBKT * 2;  // 1172 blocks, 128 dst nodes each

    lgcn_spmm<0><<<spmm_grid, block, 0, stream>>>(
        bBase, hSplit, csr, ego0, ego_a, nullptr, nullptr, nullptr);
    lgcn_spmm<0><<<spmm_grid, block, 0, stream>>>(
        bBase, hSplit, csr, ego_a, ego_b, nullptr, nullptr, nullptr);
    lgcn_spmm<1><<<spmm_grid, block, 0, stream>>>(
        bBase, hSplit, csr, ego_b, nullptr, ego_a, ego_b, (float4*)out);
}

// Round 7
// 244.626 us; speedup vs baseline: 6.5257x; 6.5257x over previous
//
#include <hip/hip_runtime.h>

#define U_CNT 100000
#define I_CNT 50000
#define D_DIM 64
#define N_NODES 150000            // U + I
#define CHUNK 4096                // edges per block in passes A/B
#define NBKT 586                  // ceil(N_NODES/256) coarse buckets (256 nodes each)
#define CCAP 3584                 // LDS edge cache per bucket (max bucket ~3.4K)

// ---------- bf16 helpers ----------
__device__ __forceinline__ float blo(unsigned u) { return __uint_as_float(u << 16); }
__device__ __forceinline__ float bhi(unsigned u) { return __uint_as_float(u & 0xFFFF0000u); }
__device__ __forceinline__ unsigned f2b(float f) {  // fp32 -> bf16 bits, RNE
    unsigned b = __float_as_uint(f);
    return (b + 0x7FFFu + ((b >> 16) & 1u)) >> 16;
}
__device__ __forceinline__ unsigned pack2(float a, float b) {
    return f2b(a) | (f2b(b) << 16);
}

// ---------- Pass A: coarse LDS histogram -> global bucket counts (+ fused convert) ----------
__global__ void bucket_hist(const int* __restrict__ dst, int* __restrict__ bCnt,
                            int nE,
                            const float4* __restrict__ user4,
                            const float4* __restrict__ item4,
                            uint2* __restrict__ ego0, int n4u, int n4) {
    __shared__ int h[NBKT];
    for (int i = threadIdx.x; i < NBKT; i += blockDim.x) h[i] = 0;
    __syncthreads();
    int b = blockIdx.x;
    int beg = b * CHUNK, end = min(nE, beg + CHUNK);
    for (int e = beg + (int)threadIdx.x; e < end; e += blockDim.x)
        atomicAdd(&h[dst[e] >> 8], 1);
    __syncthreads();
    for (int i = threadIdx.x; i < NBKT; i += blockDim.x)
        if (h[i] > 0) atomicAdd(&bCnt[i], h[i]);
    // fused streaming fp32->bf16 convert (independent work; this kernel is light)
    int gsz = gridDim.x * blockDim.x;
    for (int i = blockIdx.x * blockDim.x + threadIdx.x; i < n4; i += gsz) {
        float4 f = (i < n4u) ? user4[i] : item4[i - n4u];
        ego0[i] = make_uint2(pack2(f.x, f.y), pack2(f.z, f.w));
    }
}

// ---------- exclusive scan of 586 bucket counts (single block) ----------
__global__ void scan586(const int* __restrict__ bCnt, int* __restrict__ bBase, int nE) {
    __shared__ int sm[1024];
    int t = threadIdx.x;
    int v = (t < NBKT) ? bCnt[t] : 0;
    sm[t] = v;
    __syncthreads();
    for (int off = 1; off < 1024; off <<= 1) {
        int x = (t >= off) ? sm[t - off] : 0;
        __syncthreads();
        sm[t] += x;
        __syncthreads();
    }
    if (t < NBKT) bBase[t] = sm[t] - v;  // exclusive
    if (t == 0) bBase[NBKT] = nE;
}

// ---------- Pass B: two-pass scatter with global range reservation ----------
// record: x = src (18b) | finebin (8b) << 18 ; y = val bits
__global__ void bucket_scatter(const int* __restrict__ src, const int* __restrict__ dst,
                               const float* __restrict__ val,
                               const int* __restrict__ bBase, int* __restrict__ bCursor,
                               uint2* __restrict__ tmp, int nE) {
    __shared__ int cnt[NBKT];
    __shared__ int cur[NBKT];
    int b = blockIdx.x;
    for (int i = threadIdx.x; i < NBKT; i += blockDim.x) cnt[i] = 0;
    __syncthreads();
    int beg = b * CHUNK, end = min(nE, beg + CHUNK);
    for (int e = beg + (int)threadIdx.x; e < end; e += blockDim.x)
        atomicAdd(&cnt[dst[e] >> 8], 1);
    __syncthreads();
    for (int i = threadIdx.x; i < NBKT; i += blockDim.x) {
        int c = cnt[i];
        cur[i] = (c > 0) ? (bBase[i] + atomicAdd(&bCursor[i], c)) : 0;
    }
    __syncthreads();
    for (int e = beg + (int)threadIdx.x; e < end; e += blockDim.x) {
        int d = dst[e];
        int pos = atomicAdd(&cur[d >> 8], 1);
        tmp[pos] = make_uint2((unsigned)src[e] | ((unsigned)(d & 255) << 18),
                              __float_as_uint(val[e]));
    }
}

// ---------- Pass C: per-bucket fine sort -> csr + row_ptr ----------
__global__ void bucket_build(const int* __restrict__ bBase, const uint2* __restrict__ tmp,
                             int2* __restrict__ csr, int* __restrict__ row_ptr,
                             int nE) {
    __shared__ int hist[256];
    __shared__ int scanbuf[256];
    __shared__ int cur[256];
    __shared__ uint2 cache[CCAP];
    int bkt  = blockIdx.x;
    int base = bBase[bkt];
    int endp = bBase[bkt + 1];
    int size = endp - base;
    int nbins = min(256, N_NODES - bkt * 256);
    int t = threadIdx.x;

    hist[t] = 0;
    __syncthreads();
    bool cached = (size <= CCAP);
    for (int k = t; k < size; k += blockDim.x) {
        uint2 r = tmp[base + k];
        if (cached) cache[k] = r;
        atomicAdd(&hist[(r.x >> 18) & 255], 1);
    }
    __syncthreads();
    // inclusive scan (Hillis-Steele) -> exclusive per-thread
    int v = hist[t];
    scanbuf[t] = v;
    __syncthreads();
    for (int off = 1; off < 256; off <<= 1) {
        int x = (t >= off) ? scanbuf[t - off] : 0;
        __syncthreads();
        scanbuf[t] += x;
        __syncthreads();
    }
    int ex = scanbuf[t] - v;
    if (t < nbins) row_ptr[bkt * 256 + t] = base + ex;
    cur[t] = ex;
    __syncthreads();
    if (bkt == NBKT - 1) {
        if (t == 0) row_ptr[N_NODES] = nE;
        if (t < 4)  csr[nE + t] = make_int2(0, 0);  // spmm prefetch pad
    }
    for (int k = t; k < size; k += blockDim.x) {
        uint2 r = cached ? cache[k] : tmp[base + k];
        int f = (r.x >> 18) & 255;
        int p = atomicAdd(&cur[f], 1);
        csr[base + p] = make_int2((int)(r.x & 0x3FFFFu), (int)r.y);
    }
}

// ---------- gather SpMM: 8 lanes/node, 16 B (8 bf16) per lane ----------
// Best verified shape across 4 structural variants: 32 VGPR, ~52% occupancy,
// ~42 us/layer. Limiter: L2-miss service rate for random 128 B gathers from a
// 19.2 MB table (per-XCD L2 = 4 MB); sorting/balancing variants all land at
// the same 42 us, edge-parallel LDS-accum is 11x worse (LDS-atomic wall).
__device__ __forceinline__ void fma8(float (&acc)[8], float v, uint4 g) {
    acc[0] = fmaf(v, blo(g.x), acc[0]); acc[1] = fmaf(v, bhi(g.x), acc[1]);
    acc[2] = fmaf(v, blo(g.y), acc[2]); acc[3] = fmaf(v, bhi(g.y), acc[3]);
    acc[4] = fmaf(v, blo(g.z), acc[4]); acc[5] = fmaf(v, bhi(g.z), acc[5]);
    acc[6] = fmaf(v, blo(g.w), acc[6]); acc[7] = fmaf(v, bhi(g.w), acc[7]);
}

template <int FINAL>
__global__ void lgcn_spmm(const int* __restrict__ row_ptr,
                          const int2* __restrict__ csr,
                          const uint4* __restrict__ ego_in,
                          uint4* __restrict__ ego_out,
                          const uint4* __restrict__ egoA,
                          const uint4* __restrict__ egoB,
                          float4* __restrict__ out) {
    int node = (blockIdx.x * blockDim.x + threadIdx.x) >> 3;
    int l    = threadIdx.x & 7;
    if (node >= N_NODES) return;
    int beg = row_ptr[node];
    int end = row_ptr[node + 1];

    float a0[8] = {0, 0, 0, 0, 0, 0, 0, 0};
    float a1[8] = {0, 0, 0, 0, 0, 0, 0, 0};

    int2 e0 = csr[beg], e1 = csr[beg + 1], e2 = csr[beg + 2], e3 = csr[beg + 3];
    int j = beg;
    while (j + 4 <= end) {
        uint4 x0 = ego_in[(size_t)e0.x * 8 + l];
        uint4 x1 = ego_in[(size_t)e1.x * 8 + l];
        uint4 x2 = ego_in[(size_t)e2.x * 8 + l];
        uint4 x3 = ego_in[(size_t)e3.x * 8 + l];
        int2 n0 = csr[j + 4], n1 = csr[j + 5], n2 = csr[j + 6], n3 = csr[j + 7];
        fma8(a0, __int_as_float(e0.y), x0);
        fma8(a1, __int_as_float(e1.y), x1);
        fma8(a0, __int_as_float(e2.y), x2);
        fma8(a1, __int_as_float(e3.y), x3);
        e0 = n0; e1 = n1; e2 = n2; e3 = n3;
        j += 4;
    }
    int rem = end - j;  // 0..3
    if (rem > 0) fma8(a0, __int_as_float(e0.y), ego_in[(size_t)e0.x * 8 + l]);
    if (rem > 1) fma8(a1, __int_as_float(e1.y), ego_in[(size_t)e1.x * 8 + l]);
    if (rem > 2) fma8(a0, __int_as_float(e2.y), ego_in[(size_t)e2.x * 8 + l]);

    float acc[8];
#pragma unroll
    for (int k = 0; k < 8; ++k) acc[k] = a0[k] + a1[k];

    if (!FINAL) {
        uint4 r;
        r.x = pack2(acc[0], acc[1]); r.y = pack2(acc[2], acc[3]);
        r.z = pack2(acc[4], acc[5]); r.w = pack2(acc[6], acc[7]);
        ego_out[(size_t)node * 8 + l] = r;
    } else {
        uint4 a = egoA[(size_t)node * 8 + l];
        uint4 b = egoB[(size_t)node * 8 + l];
        const float s = 1.0f / 3.0f;
        float4 o0, o1;
        o0.x = (blo(a.x) + blo(b.x) + acc[0]) * s;
        o0.y = (bhi(a.x) + bhi(b.x) + acc[1]) * s;
        o0.z = (blo(a.y) + blo(b.y) + acc[2]) * s;
        o0.w = (bhi(a.y) + bhi(b.y) + acc[3]) * s;
        o1.x = (blo(a.z) + blo(b.z) + acc[4]) * s;
        o1.y = (bhi(a.z) + bhi(b.z) + acc[5]) * s;
        o1.z = (blo(a.w) + blo(b.w) + acc[6]) * s;
        o1.w = (bhi(a.w) + bhi(b.w) + acc[7]) * s;
        size_t ob = (size_t)node * 16 + 2 * l;
        out[ob]     = o0;
        out[ob + 1] = o1;
    }
}

static inline size_t align_up(size_t x, size_t a) { return (x + a - 1) & ~(a - 1); }

extern "C" void kernel_launch(void* const* d_in, const int* in_sizes, int n_in,
                              void* d_out, int out_size, void* d_ws, size_t ws_size,
                              hipStream_t stream) {
    const float* user_emb  = (const float*)d_in[0];
    const float* item_emb  = (const float*)d_in[1];
    const int*   edge_src  = (const int*)d_in[2];
    const int*   edge_dst  = (const int*)d_in[3];
    const float* edge_vals = (const float*)d_in[4];
    const int    nE        = in_sizes[2];  // 2E = 1.2M

    float* out = (float*)d_out;
    const size_t nd = (size_t)N_NODES * D_DIM;

    const int NB_B = (nE + CHUNK - 1) / CHUNK;  // 293

    // ---- ws layout ----
    size_t off = 0;
    char* base = (char*)d_ws;
    int2*  csr     = (int2*)(base + off);  off = align_up(off + (size_t)(nE + 4) * sizeof(int2), 256);
    int*   row_ptr = (int*)(base + off);   off = align_up(off + (size_t)(N_NODES + 1) * 4, 256);
    uint2* tmp     = (uint2*)(base + off); off = align_up(off + (size_t)nE * sizeof(uint2), 256);
    int*   bCnt    = (int*)(base + off);   off = align_up(off + (size_t)NBKT * 4, 256);
    int*   bCursor = (int*)(base + off);   off = align_up(off + (size_t)NBKT * 4, 256);
    int*   bBase   = (int*)(base + off);   off = align_up(off + (size_t)(NBKT + 1) * 4, 256);
    uint4* ego0    = (uint4*)(base + off); off = align_up(off + (size_t)N_NODES * 128, 256);
    uint4* ego_a   = (uint4*)(base + off); off = align_up(off + (size_t)N_NODES * 128, 256);
    uint4* ego_b   = (uint4*)(base + off); off = align_up(off + (size_t)N_NODES * 128, 256);

    const int block = 256;
    const int n4  = (int)(nd / 4);
    const int n4u = U_CNT * D_DIM / 4;

    // ---- CSR build: hist -> scan -> reserve+scatter -> fine sort ----
    hipMemsetAsync(bCnt, 0, 2 * align_up((size_t)NBKT * 4, 256), stream);  // bCnt + bCursor
    bucket_hist<<<NB_B, block, 0, stream>>>(edge_dst, bCnt, nE,
        (const float4*)user_emb, (const float4*)item_emb, (uint2*)ego0, n4u, n4);
    scan586<<<1, 1024, 0, stream>>>(bCnt, bBase, nE);
    bucket_scatter<<<NB_B, block, 0, stream>>>(edge_src, edge_dst, edge_vals,
                                               bBase, bCursor, tmp, nE);
    bucket_build<<<NBKT, block, 0, stream>>>(bBase, tmp, csr, row_ptr, nE);

    // ---- 3 SpMM layers (bf16 gather, 8 lanes/node, x4 unroll) ----
    const size_t threads = (size_t)N_NODES * 8;
    const int spmm_grid = (int)((threads + block - 1) / block);

    lgcn_spmm<0><<<spmm_grid, block, 0, stream>>>(
        row_ptr, csr, ego0, ego_a, nullptr, nullptr, nullptr);
    lgcn_spmm<0><<<spmm_grid, block, 0, stream>>>(
        row_ptr, csr, ego_a, ego_b, nullptr, nullptr, nullptr);
    lgcn_spmm<1><<<spmm_grid, block, 0, stream>>>(
        row_ptr, csr, ego_b, nullptr, ego_a, ego_b, (float4*)out);
}